// Round 1
// baseline (415.024 us; speedup 1.0000x reference)
//
#include <hip/hip_runtime.h>

using bf16x8  = __attribute__((ext_vector_type(8))) __bf16;
using f32x4   = __attribute__((ext_vector_type(4))) float;
using short8  = __attribute__((ext_vector_type(8))) short;
using float4v = __attribute__((ext_vector_type(4))) float;

static __device__ __forceinline__ unsigned short f2bf(float f) {
    unsigned int u = __float_as_uint(f);
    unsigned int r = (u + 0x7fffu + ((u >> 16) & 1u)) >> 16;  // RNE
    return (unsigned short)r;
}
static __device__ __forceinline__ float bf2f(unsigned short s) {
    return __uint_as_float(((unsigned int)s) << 16);
}
static __device__ __forceinline__ bf16x8 as_bf(short8 s) {
    return __builtin_bit_cast(bf16x8, s);
}

// ---- weight prep: fp32 [k][c] -> bf16 transposed [c][k] ----
// wqkvT: [384][256]  (c<128: Wq col c; c<256: Wk col c-128; else Wv col c-256)
// woT:   [128][128]  woT[c][k] = Wo[k][c]
__global__ void prep_weights(const float* __restrict__ Wq, const float* __restrict__ Wk,
                             const float* __restrict__ Wv, const float* __restrict__ Wo,
                             unsigned short* __restrict__ wqkvT, unsigned short* __restrict__ woT) {
    int idx = blockIdx.x * 256 + threadIdx.x;  // 448*256 = 114688 = 384*256 + 128*128
    if (idx < 384 * 256) {
        int c = idx >> 8, k = idx & 255;
        float v = (c < 128) ? Wq[k * 128 + c]
                : (c < 256) ? Wk[k * 128 + (c - 128)]
                            : Wv[k * 128 + (c - 256)];
        wqkvT[idx] = f2bf(v);
    } else {
        int j = idx - 384 * 256;
        int c = j >> 7, k = j & 127;
        woT[j] = f2bf(Wo[k * 128 + c]);
    }
}

// ---- fused: per (b,n) block: QKV gemm -> 16 tiny causal attentions -> out proj ----
__global__ __launch_bounds__(256, 1)
void fused_attn(const float* __restrict__ X, const float* __restrict__ STE,
                const float* __restrict__ bq, const float* __restrict__ bk,
                const float* __restrict__ bv, const float* __restrict__ bo,
                const unsigned short* __restrict__ wqkvT, const unsigned short* __restrict__ woT,
                float* __restrict__ out) {
    __shared__ unsigned short xc[64][264];      // [t][k] bf16, pad 256->264 (2-way max aliasing)
    __shared__ unsigned short qkv[3][64][136];  // [q/k/v][t][c] bf16, pad 128->136 (16B-aligned rows)

    const int tid  = threadIdx.x;
    const int lane = tid & 63;
    const int w    = tid >> 6;       // wave 0..3
    const int bid  = blockIdx.x;
    const int n    = bid & 255;
    const int b    = bid >> 8;
    const int lr   = lane & 15;      // A-row / B-col / D-col within 16-tile
    const int lg   = lane >> 4;      // k-group / D row-group

    // ---------- stage Xc = [X | STE] rows (b, t=0..63, n, :) as bf16 ----------
    const float* xbase = X   + (size_t)(b * 16384 + n) * 128;  // + t*32768 + d
    const float* sbase = STE + (size_t)(b * 16384 + n) * 128;
    #pragma unroll
    for (int it = 0; it < 16; ++it) {
        int f4 = tid + it * 256;       // 0..4095 over [64 t][64 float4]
        int t  = f4 >> 6;
        int j  = f4 & 63;
        const float* src = (j < 32) ? (xbase + (size_t)t * 32768 + j * 4)
                                    : (sbase + (size_t)t * 32768 + (j - 32) * 4);
        float4v v = *reinterpret_cast<const float4v*>(src);
        unsigned int lo = (unsigned int)f2bf(v[0]) | ((unsigned int)f2bf(v[1]) << 16);
        unsigned int hi = (unsigned int)f2bf(v[2]) | ((unsigned int)f2bf(v[3]) << 16);
        unsigned int* dst = reinterpret_cast<unsigned int*>(&xc[t][j * 4]);
        dst[0] = lo; dst[1] = hi;
    }
    __syncthreads();

    // ---------- GEMM1: [64 t][384 c] = Xc[64][256] @ Wqkv[256][384], +bias, relu ----------
    f32x4 acc[4][6];
    #pragma unroll
    for (int m = 0; m < 4; ++m)
        #pragma unroll
        for (int i = 0; i < 6; ++i)
            acc[m][i] = f32x4{0.f, 0.f, 0.f, 0.f};

    #pragma unroll 2
    for (int ks = 0; ks < 8; ++ks) {
        int kb = ks * 32;
        bf16x8 a[4];
        #pragma unroll
        for (int m = 0; m < 4; ++m)
            a[m] = as_bf(*reinterpret_cast<const short8*>(&xc[m * 16 + lr][kb + lg * 8]));
        bf16x8 bfr[6];
        #pragma unroll
        for (int i = 0; i < 6; ++i) {
            int c0 = (w * 6 + i) * 16;
            bfr[i] = as_bf(*reinterpret_cast<const short8*>(
                wqkvT + (size_t)(c0 + lr) * 256 + kb + lg * 8));
        }
        #pragma unroll
        for (int m = 0; m < 4; ++m)
            #pragma unroll
            for (int i = 0; i < 6; ++i)
                acc[m][i] = __builtin_amdgcn_mfma_f32_16x16x32_bf16(a[m], bfr[i], acc[m][i], 0, 0, 0);
    }

    // epilogue: bias + relu -> bf16 LDS
    #pragma unroll
    for (int i = 0; i < 6; ++i) {
        int c  = (w * 6 + i) * 16 + lr;
        int qi = c >> 7;      // 0=Q 1=K 2=V (uniform within tile)
        int cc = c & 127;
        const float* bias = (qi == 0) ? bq : (qi == 1) ? bk : bv;
        float bvv = bias[cc];
        #pragma unroll
        for (int m = 0; m < 4; ++m)
            #pragma unroll
            for (int r = 0; r < 4; ++r) {
                int t = m * 16 + lg * 4 + r;
                qkv[qi][t][cc] = f2bf(fmaxf(acc[m][i][r] + bvv, 0.f));
            }
    }
    __syncthreads();

    // ---------- attention: wave w handles chunks c = 4w..4w+3; lane = t row ----------
    const int t = lane;
    #pragma unroll 1
    for (int ci = 0; ci < 4; ++ci) {
        int cb = (w * 4 + ci) * 8;   // feature base of this chunk
        float q[8];
        {
            short8 qs = *reinterpret_cast<const short8*>(&qkv[0][t][cb]);
            #pragma unroll
            for (int h = 0; h < 8; ++h) q[h] = bf2f((unsigned short)qs[h]);
        }
        // pass 1: causal row max of scaled scores
        float mx = -1e30f;
        for (int s = 0; s < 64; ++s) {
            short8 kr = *reinterpret_cast<const short8*>(&qkv[1][s][cb]);  // uniform -> broadcast
            float d = 0.f;
            #pragma unroll
            for (int h = 0; h < 8; ++h) d += q[h] * bf2f((unsigned short)kr[h]);
            d *= 0.25f;                      // 1/sqrt(D_H=16)
            if (s <= t) mx = fmaxf(mx, d);
        }
        // pass 2: exp-sum + PV accumulate
        float l = 0.f;
        float o[8] = {0.f, 0.f, 0.f, 0.f, 0.f, 0.f, 0.f, 0.f};
        for (int s = 0; s < 64; ++s) {
            short8 kr = *reinterpret_cast<const short8*>(&qkv[1][s][cb]);
            short8 vr = *reinterpret_cast<const short8*>(&qkv[2][s][cb]);
            float d = 0.f;
            #pragma unroll
            for (int h = 0; h < 8; ++h) d += q[h] * bf2f((unsigned short)kr[h]);
            d *= 0.25f;
            float p = (s <= t) ? __expf(d - mx) : 0.f;
            l += p;
            #pragma unroll
            for (int h = 0; h < 8; ++h) o[h] += p * bf2f((unsigned short)vr[h]);
        }
        float inv = 1.f / l;
        short8 pk;
        #pragma unroll
        for (int h = 0; h < 8; ++h) pk[h] = (short)f2bf(o[h] * inv);
        // overwrite Q region in place (race-free: columns disjoint per wave, row = own lane)
        *reinterpret_cast<short8*>(&qkv[0][t][cb]) = pk;
    }
    __syncthreads();

    // ---------- GEMM2: out[64 t][128 c] = attnout[64][128] @ Wo[128][128], +bo, relu ----------
    f32x4 acc2[4][2];
    #pragma unroll
    for (int m = 0; m < 4; ++m)
        #pragma unroll
        for (int i = 0; i < 2; ++i)
            acc2[m][i] = f32x4{0.f, 0.f, 0.f, 0.f};

    #pragma unroll
    for (int ks = 0; ks < 4; ++ks) {
        int kb = ks * 32;
        bf16x8 a[4];
        #pragma unroll
        for (int m = 0; m < 4; ++m)
            a[m] = as_bf(*reinterpret_cast<const short8*>(&qkv[0][m * 16 + lr][kb + lg * 8]));
        bf16x8 bb[2];
        #pragma unroll
        for (int i = 0; i < 2; ++i) {
            int c0 = (w + 4 * i) * 16;
            bb[i] = as_bf(*reinterpret_cast<const short8*>(woT + (size_t)(c0 + lr) * 128 + kb + lg * 8));
        }
        #pragma unroll
        for (int m = 0; m < 4; ++m)
            #pragma unroll
            for (int i = 0; i < 2; ++i)
                acc2[m][i] = __builtin_amdgcn_mfma_f32_16x16x32_bf16(a[m], bb[i], acc2[m][i], 0, 0, 0);
    }

    float* obase = out + (size_t)(b * 16384 + n) * 128;  // + t*32768 + c
    #pragma unroll
    for (int i = 0; i < 2; ++i) {
        int c = (w + 4 * i) * 16 + lr;
        float bias = bo[c];
        #pragma unroll
        for (int m = 0; m < 4; ++m)
            #pragma unroll
            for (int r = 0; r < 4; ++r) {
                int tt = m * 16 + lg * 4 + r;
                obase[(size_t)tt * 32768 + c] = fmaxf(acc2[m][i][r] + bias, 0.f);
            }
    }
}

extern "C" void kernel_launch(void* const* d_in, const int* in_sizes, int n_in,
                              void* d_out, int out_size, void* d_ws, size_t ws_size,
                              hipStream_t stream) {
    const float* X   = (const float*)d_in[0];
    const float* STE = (const float*)d_in[1];
    const float* Wq  = (const float*)d_in[2];
    const float* bq  = (const float*)d_in[3];
    const float* Wk  = (const float*)d_in[4];
    const float* bk  = (const float*)d_in[5];
    const float* Wv  = (const float*)d_in[6];
    const float* bv  = (const float*)d_in[7];
    const float* Wo  = (const float*)d_in[8];
    const float* bo  = (const float*)d_in[9];
    float* out = (float*)d_out;

    unsigned short* wqkvT = (unsigned short*)d_ws;            // 384*256 bf16 = 196608 B
    unsigned short* woT   = wqkvT + 384 * 256;                // 128*128 bf16 =  32768 B

    prep_weights<<<448, 256, 0, stream>>>(Wq, Wk, Wv, Wo, wqkvT, woT);
    fused_attn<<<2048, 256, 0, stream>>>(X, STE, bq, bk, bv, bo, wqkvT, woT, out);
}

// Round 2
// 122.693 us; speedup vs baseline: 3.3826x; 3.3826x over previous
//
#include <hip/hip_runtime.h>

using bf16x8  = __attribute__((ext_vector_type(8))) __bf16;
using f32x4   = __attribute__((ext_vector_type(4))) float;
using short8  = __attribute__((ext_vector_type(8))) short;
using float4v = __attribute__((ext_vector_type(4))) float;
using uint2v  = __attribute__((ext_vector_type(2))) unsigned int;

static __device__ __forceinline__ unsigned short f2bf(float f) {
    unsigned int u = __float_as_uint(f);
    unsigned int r = (u + 0x7fffu + ((u >> 16) & 1u)) >> 16;  // RNE
    return (unsigned short)r;
}
static __device__ __forceinline__ bf16x8 as_bf(short8 s) {
    return __builtin_bit_cast(bf16x8, s);
}

// ---- weight prep: fp32 [k][c] -> bf16 transposed [c][k] ----
__global__ void prep_weights(const float* __restrict__ Wq, const float* __restrict__ Wk,
                             const float* __restrict__ Wv, const float* __restrict__ Wo,
                             unsigned short* __restrict__ wqkvT, unsigned short* __restrict__ woT) {
    int idx = blockIdx.x * 256 + threadIdx.x;
    if (idx < 384 * 256) {
        int c = idx >> 8, k = idx & 255;
        float v = (c < 128) ? Wq[k * 128 + c]
                : (c < 256) ? Wk[k * 128 + (c - 128)]
                            : Wv[k * 128 + (c - 256)];
        wqkvT[idx] = f2bf(v);
    } else {
        int j = idx - 384 * 256;
        int c = j >> 7, k = j & 127;
        woT[j] = f2bf(Wo[k * 128 + c]);
    }
}

// LDS layout (XOR-swizzled, 81920 B total -> 2 blocks/CU):
//  SQ0: Q  [64][128] bf16, row 256B, swz ^((t&7)<<4)   (later reused as attn-out)
//  SK0: K  [64][128] bf16, row 256B, swz
//  SV0: Vt [128][64] bf16, row 128B, swz ^((c&7)<<4)
//  SA0: xc [64][256] bf16, row 512B, swz  (later reused as P buffers, [64][40] per wave)
__global__ __launch_bounds__(256, 2)
void fused_attn(const float* __restrict__ X, const float* __restrict__ STE,
                const float* __restrict__ bq, const float* __restrict__ bk,
                const float* __restrict__ bv, const float* __restrict__ bo,
                const unsigned short* __restrict__ wqkvT, const unsigned short* __restrict__ woT,
                float* __restrict__ out) {
    __shared__ __align__(16) char sm[81920];
    constexpr int SQ0 = 0, SK0 = 16384, SV0 = 32768, SA0 = 49152;

    const int tid  = threadIdx.x;
    const int lane = tid & 63;
    const int w    = tid >> 6;
    const int bid  = blockIdx.x;
    const int n    = bid & 255;
    const int b    = bid >> 8;
    const int lr   = lane & 15;
    const int lg   = lane >> 4;
    const int rsw  = (lr & 7) << 4;   // swizzle term for rows of form 16*k + lr

    // ---------- stage Xc = [X | STE] as bf16 into xc ----------
    const float* xbase = X   + (size_t)(b * 16384 + n) * 128;
    const float* sbase = STE + (size_t)(b * 16384 + n) * 128;
    #pragma unroll
    for (int it = 0; it < 16; ++it) {
        int f4 = tid + it * 256;
        int t  = f4 >> 6;
        int j  = f4 & 63;
        const float* src = (j < 32) ? (xbase + (size_t)t * 32768 + j * 4)
                                    : (sbase + (size_t)t * 32768 + (j - 32) * 4);
        float4v v = *reinterpret_cast<const float4v*>(src);
        uint2v d;
        d[0] = (unsigned int)f2bf(v[0]) | ((unsigned int)f2bf(v[1]) << 16);
        d[1] = (unsigned int)f2bf(v[2]) | ((unsigned int)f2bf(v[3]) << 16);
        *reinterpret_cast<uint2v*>(sm + SA0 + (t << 9) + ((j * 8) ^ ((t & 7) << 4))) = d;
    }
    __syncthreads();

    // ---------- GEMM1: QKV = Xc[64][256] @ Wqkv[256][384] ----------
    f32x4 acc[4][6];
    #pragma unroll
    for (int m = 0; m < 4; ++m)
        #pragma unroll
        for (int i = 0; i < 6; ++i)
            acc[m][i] = f32x4{0.f, 0.f, 0.f, 0.f};

    #pragma unroll 2
    for (int ks = 0; ks < 8; ++ks) {
        bf16x8 a[4];
        #pragma unroll
        for (int m = 0; m < 4; ++m)
            a[m] = as_bf(*reinterpret_cast<const short8*>(
                sm + SA0 + ((m * 16 + lr) << 9) + ((ks * 64 + lg * 16) ^ rsw)));
        bf16x8 bfr[6];
        #pragma unroll
        for (int i = 0; i < 6; ++i) {
            int c0 = (w * 6 + i) * 16;
            bfr[i] = as_bf(*reinterpret_cast<const short8*>(
                wqkvT + (size_t)(c0 + lr) * 256 + ks * 32 + lg * 8));
        }
        #pragma unroll
        for (int m = 0; m < 4; ++m)
            #pragma unroll
            for (int i = 0; i < 6; ++i)
                acc[m][i] = __builtin_amdgcn_mfma_f32_16x16x32_bf16(a[m], bfr[i], acc[m][i], 0, 0, 0);
    }

    // epilogue: bias+relu -> Q, K (scalar u16, swizzled) and Vt (transposed, b64)
    #pragma unroll
    for (int i = 0; i < 6; ++i) {
        int c = (w * 6 + i) * 16 + lr;
        if (c < 256) {
            int qi = c >> 7, cc = c & 127;
            char* base = sm + (qi ? SK0 : SQ0);
            float bvv = (qi ? bk : bq)[cc];
            #pragma unroll
            for (int m = 0; m < 4; ++m)
                #pragma unroll
                for (int r = 0; r < 4; ++r) {
                    int t = m * 16 + lg * 4 + r;
                    *reinterpret_cast<unsigned short*>(base + (t << 8) + ((cc * 2) ^ ((t & 7) << 4)))
                        = f2bf(fmaxf(acc[m][i][r] + bvv, 0.f));
                }
        } else {
            int cv = c - 256;
            float bvv = bv[cv];
            #pragma unroll
            for (int m = 0; m < 4; ++m) {
                uint2v d;
                d[0] = (unsigned int)f2bf(fmaxf(acc[m][i][0] + bvv, 0.f))
                     | ((unsigned int)f2bf(fmaxf(acc[m][i][1] + bvv, 0.f)) << 16);
                d[1] = (unsigned int)f2bf(fmaxf(acc[m][i][2] + bvv, 0.f))
                     | ((unsigned int)f2bf(fmaxf(acc[m][i][3] + bvv, 0.f)) << 16);
                *reinterpret_cast<uint2v*>(
                    sm + SV0 + (cv << 7) + ((m * 32 + lg * 8) ^ ((cv & 7) << 4))) = d;
            }
        }
    }
    __syncthreads();

    // ---------- attention: wave w owns chunks 4w..4w+3 ----------
    const f32x4 zf = {0.f, 0.f, 0.f, 0.f};
    const short8 z8 = {0, 0, 0, 0, 0, 0, 0, 0};
    char* Pb = sm + SA0 + w * 5120;   // per-wave P buffer [64][40] bf16 (one 32-wide s-half)

    #pragma unroll 1
    for (int ci = 0; ci < 4; ++ci) {
        const int cb  = (w * 4 + ci) * 8;
        const int cbB = cb * 2;

        // S^T = K * Q^T  (h in k-slot lg=0 only; slots 1-3 zero)
        bf16x8 kf[4], qf[4];
        #pragma unroll
        for (int st = 0; st < 4; ++st)
            kf[st] = (lg == 0)
                ? as_bf(*reinterpret_cast<const short8*>(sm + SK0 + ((st * 16 + lr) << 8) + (cbB ^ rsw)))
                : as_bf(z8);
        #pragma unroll
        for (int nt = 0; nt < 4; ++nt)
            qf[nt] = (lg == 0)
                ? as_bf(*reinterpret_cast<const short8*>(sm + SQ0 + ((nt * 16 + lr) << 8) + (cbB ^ rsw)))
                : as_bf(z8);

        f32x4 s[4][4];
        #pragma unroll
        for (int st = 0; st < 4; ++st)
            #pragma unroll
            for (int nt = 0; nt < 4; ++nt)
                s[st][nt] = __builtin_amdgcn_mfma_f32_16x16x32_bf16(kf[st], qf[nt], zf, 0, 0, 0);

        // softmax over s per column t (lane-local 16 values + 2 shfl_xor)
        #pragma unroll
        for (int nt = 0; nt < 4; ++nt) {
            int t_ = nt * 16 + lr;
            float e[4][4];
            float mx = -1e30f;
            #pragma unroll
            for (int st = 0; st < 4; ++st)
                #pragma unroll
                for (int r = 0; r < 4; ++r) {
                    int s_ = st * 16 + lg * 4 + r;
                    float v = s[st][nt][r] * 0.25f;   // 1/sqrt(16)
                    e[st][r] = (s_ <= t_) ? v : -1e30f;
                    mx = fmaxf(mx, e[st][r]);
                }
            mx = fmaxf(mx, __shfl_xor(mx, 16));
            mx = fmaxf(mx, __shfl_xor(mx, 32));
            float l = 0.f;
            #pragma unroll
            for (int st = 0; st < 4; ++st)
                #pragma unroll
                for (int r = 0; r < 4; ++r) {
                    float p = __expf(e[st][r] - mx);  // masked -> exp(-huge) = 0
                    l += p;
                    s[st][nt][r] = p;
                }
            l += __shfl_xor(l, 16);
            l += __shfl_xor(l, 32);
            float inv = 1.f / l;
            #pragma unroll
            for (int st = 0; st < 4; ++st)
                #pragma unroll
                for (int r = 0; r < 4; ++r)
                    s[st][nt][r] *= inv;
        }

        // PV: O^T = V^T * P, s split into two 32-wide halves through the P buffer
        f32x4 o[4] = {zf, zf, zf, zf};
        #pragma unroll
        for (int ks = 0; ks < 2; ++ks) {
            #pragma unroll
            for (int bh = 0; bh < 2; ++bh) {
                int st = ks * 2 + bh;
                #pragma unroll
                for (int nt = 0; nt < 4; ++nt) {
                    uint2v d;
                    d[0] = (unsigned int)f2bf(s[st][nt][0]) | ((unsigned int)f2bf(s[st][nt][1]) << 16);
                    d[1] = (unsigned int)f2bf(s[st][nt][2]) | ((unsigned int)f2bf(s[st][nt][3]) << 16);
                    *reinterpret_cast<uint2v*>(Pb + (nt * 16 + lr) * 80 + bh * 32 + lg * 8) = d;
                }
            }
            int vr = min(cb + lr, 127);  // rows >=128 feed ignored D-rows h>=8
            bf16x8 vf = as_bf(*reinterpret_cast<const short8*>(
                sm + SV0 + (vr << 7) + ((ks * 64 + lg * 16) ^ ((vr & 7) << 4))));
            #pragma unroll
            for (int nt = 0; nt < 4; ++nt) {
                bf16x8 pf = as_bf(*reinterpret_cast<const short8*>(Pb + (nt * 16 + lr) * 80 + lg * 16));
                o[nt] = __builtin_amdgcn_mfma_f32_16x16x32_bf16(vf, pf, o[nt], 0, 0, 0);
            }
            asm volatile("" ::: "memory");  // keep ks=1 P-writes after ks=0 P-reads
        }

        // write attn-out (h = lg*4+r, valid lg<2) into Q region, b64 per nt
        if (lg < 2) {
            #pragma unroll
            for (int nt = 0; nt < 4; ++nt) {
                int t_ = nt * 16 + lr;
                uint2v d;
                d[0] = (unsigned int)f2bf(o[nt][0]) | ((unsigned int)f2bf(o[nt][1]) << 16);
                d[1] = (unsigned int)f2bf(o[nt][2]) | ((unsigned int)f2bf(o[nt][3]) << 16);
                *reinterpret_cast<uint2v*>(sm + SQ0 + (t_ << 8) + ((cbB + lg * 8) ^ rsw)) = d;
            }
        }
    }
    __syncthreads();

    // ---------- GEMM2: out = aout[64][128] @ Wo[128][128] + bo, relu ----------
    f32x4 acc2[4][2];
    #pragma unroll
    for (int m = 0; m < 4; ++m)
        #pragma unroll
        for (int i = 0; i < 2; ++i)
            acc2[m][i] = zf;

    #pragma unroll
    for (int ks = 0; ks < 4; ++ks) {
        bf16x8 a2[4];
        #pragma unroll
        for (int m = 0; m < 4; ++m)
            a2[m] = as_bf(*reinterpret_cast<const short8*>(
                sm + SQ0 + ((m * 16 + lr) << 8) + ((ks * 64 + lg * 16) ^ rsw)));
        bf16x8 b2[2];
        #pragma unroll
        for (int i = 0; i < 2; ++i) {
            int c0 = (w + 4 * i) * 16;
            b2[i] = as_bf(*reinterpret_cast<const short8*>(
                woT + (size_t)(c0 + lr) * 128 + ks * 32 + lg * 8));
        }
        #pragma unroll
        for (int m = 0; m < 4; ++m)
            #pragma unroll
            for (int i = 0; i < 2; ++i)
                acc2[m][i] = __builtin_amdgcn_mfma_f32_16x16x32_bf16(a2[m], b2[i], acc2[m][i], 0, 0, 0);
    }

    float* obase = out + (size_t)(b * 16384 + n) * 128;
    #pragma unroll
    for (int i = 0; i < 2; ++i) {
        int c = (w + 4 * i) * 16 + lr;
        float bias = bo[c];
        #pragma unroll
        for (int m = 0; m < 4; ++m)
            #pragma unroll
            for (int r = 0; r < 4; ++r) {
                int tt = m * 16 + lg * 4 + r;
                obase[(size_t)tt * 32768 + c] = fmaxf(acc2[m][i][r] + bias, 0.f);
            }
    }
}

extern "C" void kernel_launch(void* const* d_in, const int* in_sizes, int n_in,
                              void* d_out, int out_size, void* d_ws, size_t ws_size,
                              hipStream_t stream) {
    const float* X   = (const float*)d_in[0];
    const float* STE = (const float*)d_in[1];
    const float* Wq  = (const float*)d_in[2];
    const float* bq  = (const float*)d_in[3];
    const float* Wk  = (const float*)d_in[4];
    const float* bk  = (const float*)d_in[5];
    const float* Wv  = (const float*)d_in[6];
    const float* bv  = (const float*)d_in[7];
    const float* Wo  = (const float*)d_in[8];
    const float* bo  = (const float*)d_in[9];
    float* out = (float*)d_out;

    unsigned short* wqkvT = (unsigned short*)d_ws;
    unsigned short* woT   = wqkvT + 384 * 256;

    prep_weights<<<448, 256, 0, stream>>>(Wq, Wk, Wv, Wo, wqkvT, woT);
    fused_attn<<<2048, 256, 0, stream>>>(X, STE, bq, bk, bv, bo, wqkvT, woT, out);
}

// Round 3
// 90.917 us; speedup vs baseline: 4.5649x; 1.3495x over previous
//
#include <hip/hip_runtime.h>

using bf16x8  = __attribute__((ext_vector_type(8))) __bf16;
using f32x4   = __attribute__((ext_vector_type(4))) float;
using short8  = __attribute__((ext_vector_type(8))) short;
using float4v = __attribute__((ext_vector_type(4))) float;
using uint2v  = __attribute__((ext_vector_type(2))) unsigned int;

#if __has_builtin(__builtin_amdgcn_exp2f)
#define EXP2F(x) __builtin_amdgcn_exp2f(x)
#else
#define EXP2F(x) __expf((x) * 0.6931472f)
#endif
#if __has_builtin(__builtin_amdgcn_rcpf)
#define RCPF(x) __builtin_amdgcn_rcpf(x)
#else
#define RCPF(x) (1.f / (x))
#endif

static __device__ __forceinline__ unsigned short bfu(float f) {
    return __builtin_bit_cast(unsigned short, (__bf16)f);
}
static __device__ __forceinline__ unsigned int pkbf(float a, float b) {
    return (unsigned int)bfu(a) | ((unsigned int)bfu(b) << 16);
}
static __device__ __forceinline__ bf16x8 as_bf(short8 s) {
    return __builtin_bit_cast(bf16x8, s);
}

// ---- weight prep: fp32 [k][c] -> bf16 [ks][c][32] (k-tiled, lane-coalesced) ----
// wq2: 8 ks-tiles of [384 c][32 kk]; wo2: 4 ks-tiles of [128 c][32 kk]
__global__ void prep_weights(const float* __restrict__ Wq, const float* __restrict__ Wk,
                             const float* __restrict__ Wv, const float* __restrict__ Wo,
                             unsigned short* __restrict__ wq2, unsigned short* __restrict__ wo2) {
    int idx = blockIdx.x * 256 + threadIdx.x;  // 448*256 = 384*256 + 128*128
    if (idx < 384 * 256) {
        int c = idx >> 8, k = idx & 255;
        float v = (c < 128) ? Wq[k * 128 + c]
                : (c < 256) ? Wk[k * 128 + (c - 128)]
                            : Wv[k * 128 + (c - 256)];
        wq2[(k >> 5) * 12288 + (c << 5) + (k & 31)] = bfu(v);
    } else {
        int j = idx - 384 * 256;
        int c = j >> 7, k = j & 127;
        wo2[(k >> 5) * 4096 + (c << 5) + (k & 31)] = bfu(Wo[k * 128 + c]);
    }
}

// LDS (81920 B -> 2 blocks/CU):
//  SXC: xc [64 t][512B] (256 bf16), swz byte ^= (t&7)<<6; reused as P: per wave [64][128B], swz (row&7)<<4
//  SQK: qk [64 t][512B] (c 0..127 = Q / attn-out, c 128..255 = K), swz ((t&7)<<6)^((t&8)<<2)
//  SV : vt [128 cv][128B] (64 t bf16), swz (cv&7)<<4
__global__ __launch_bounds__(256, 2)
void fused_attn(const float* __restrict__ X, const float* __restrict__ STE,
                const float* __restrict__ bq, const float* __restrict__ bk,
                const float* __restrict__ bv, const float* __restrict__ bo,
                const unsigned short* __restrict__ wq2, const unsigned short* __restrict__ wo2,
                float* __restrict__ out) {
    __shared__ __align__(16) char sm[81920];
    constexpr int SXC = 0, SQK = 32768, SV = 65536;
    const float SC2 = 0.36067376f;  // 0.25 * log2(e)

    const int tid  = threadIdx.x;
    const int lane = tid & 63;
    const int w    = tid >> 6;
    const int bid  = blockIdx.x;
    const int n    = bid & 255;
    const int b    = bid >> 8;
    const int lr   = lane & 15;
    const int lg   = lane >> 4;
    const int rswA = (lr & 7) << 6;                       // xc swizzle, rows == lr (mod 16)
    const int rswQ = ((lr & 7) << 6) ^ ((lr & 8) << 2);   // qk swizzle, rows == lr (mod 16)
    const int rswP = (lr & 7) << 4;                       // P swizzle

    // ---------- stage Xc = [X | STE] as bf16 ----------
    const float* xbase = X   + (size_t)(b * 16384 + n) * 128;
    const float* sbase = STE + (size_t)(b * 16384 + n) * 128;
    #pragma unroll
    for (int it = 0; it < 16; ++it) {
        int t = w + it * 4;
        int j = lane;
        const float* src = (j < 32) ? (xbase + (size_t)t * 32768 + j * 4)
                                    : (sbase + (size_t)t * 32768 + (j - 32) * 4);
        float4v v = *reinterpret_cast<const float4v*>(src);
        uint2v d;
        d[0] = pkbf(v[0], v[1]);
        d[1] = pkbf(v[2], v[3]);
        *reinterpret_cast<uint2v*>(sm + SXC + (t << 9) + ((j * 8) ^ ((t & 7) << 6))) = d;
    }
    __syncthreads();

    // ---------- GEMM1: QKV = Xc[64][256] @ Wqkv[256][384], prefetch double-buffer ----------
    const int c0 = w * 96;
    f32x4 acc[4][6];
    #pragma unroll
    for (int m = 0; m < 4; ++m)
        #pragma unroll
        for (int i = 0; i < 6; ++i)
            acc[m][i] = f32x4{0.f, 0.f, 0.f, 0.f};

    bf16x8 bnxt[6];
    #pragma unroll
    for (int i = 0; i < 6; ++i)
        bnxt[i] = as_bf(*reinterpret_cast<const short8*>(
            wq2 + (size_t)(c0 + i * 16 + lr) * 32 + lg * 8));

    #pragma unroll
    for (int ks = 0; ks < 8; ++ks) {
        bf16x8 bcur[6];
        #pragma unroll
        for (int i = 0; i < 6; ++i) bcur[i] = bnxt[i];
        if (ks < 7) {
            #pragma unroll
            for (int i = 0; i < 6; ++i)
                bnxt[i] = as_bf(*reinterpret_cast<const short8*>(
                    wq2 + (size_t)(ks + 1) * 12288 + (size_t)(c0 + i * 16 + lr) * 32 + lg * 8));
        }
        bf16x8 a[4];
        #pragma unroll
        for (int m = 0; m < 4; ++m)
            a[m] = as_bf(*reinterpret_cast<const short8*>(
                sm + SXC + ((m * 16 + lr) << 9) + ((ks * 64 + lg * 16) ^ rswA)));
        #pragma unroll
        for (int m = 0; m < 4; ++m)
            #pragma unroll
            for (int i = 0; i < 6; ++i)
                acc[m][i] = __builtin_amdgcn_mfma_f32_16x16x32_bf16(a[m], bcur[i], acc[m][i], 0, 0, 0);
    }

    // epilogue: bias+relu -> Q,K (u16, swizzled) and Vt (transposed b64)
    #pragma unroll
    for (int i = 0; i < 6; ++i) {
        int c = c0 + i * 16 + lr;
        if (c < 256) {
            float bvv = (c < 128) ? bq[c] : bk[c & 127];
            #pragma unroll
            for (int m = 0; m < 4; ++m)
                #pragma unroll
                for (int r = 0; r < 4; ++r) {
                    int t = m * 16 + lg * 4 + r;
                    *reinterpret_cast<unsigned short*>(
                        sm + SQK + (t << 9) + ((c * 2) ^ (((t & 7) << 6) ^ ((t & 8) << 2))))
                        = bfu(fmaxf(acc[m][i][r] + bvv, 0.f));
                }
        } else {
            int cv = c - 256;
            float bvv = bv[cv];
            #pragma unroll
            for (int m = 0; m < 4; ++m) {
                uint2v d;
                d[0] = pkbf(fmaxf(acc[m][i][0] + bvv, 0.f), fmaxf(acc[m][i][1] + bvv, 0.f));
                d[1] = pkbf(fmaxf(acc[m][i][2] + bvv, 0.f), fmaxf(acc[m][i][3] + bvv, 0.f));
                *reinterpret_cast<uint2v*>(
                    sm + SV + (cv << 7) + ((m * 32 + lg * 8) ^ ((cv & 7) << 4))) = d;
            }
        }
    }
    __syncthreads();

    // ---------- attention: wave w owns chunks 4w..4w+3 ----------
    const f32x4 zf = {0.f, 0.f, 0.f, 0.f};
    const short8 z8 = {0, 0, 0, 0, 0, 0, 0, 0};
    short8 ones8;
    #pragma unroll
    for (int h = 0; h < 8; ++h) ones8[h] = (short)0x3F80;  // bf16 1.0
    char* Pb = sm + SXC + w * 8192;  // per-wave P [64 t][128B = 64 s bf16]

    #pragma unroll 1
    for (int ci = 0; ci < 4; ++ci) {
        const int cb  = (w * 4 + ci) * 8;
        const int cbB = cb * 2;

        bf16x8 kf[4], qf[4];
        #pragma unroll
        for (int j = 0; j < 4; ++j) {
            kf[j] = (lg == 0)
                ? as_bf(*reinterpret_cast<const short8*>(
                      sm + SQK + ((j * 16 + lr) << 9) + ((256 + cbB) ^ rswQ)))
                : as_bf(z8);
            qf[j] = (lg == 0)
                ? as_bf(*reinterpret_cast<const short8*>(
                      sm + SQK + ((j * 16 + lr) << 9) + (cbB ^ rswQ)))
                : as_bf(z8);
        }

        // S tiles (causal: st<=nt) -> exp2 (no max-sub) -> P bf16 (unnormalized)
        #pragma unroll
        for (int nt = 0; nt < 4; ++nt) {
            #pragma unroll
            for (int st = 0; st < 4; ++st) {
                if (st > nt) continue;
                f32x4 sv = __builtin_amdgcn_mfma_f32_16x16x32_bf16(kf[st], qf[nt], zf, 0, 0, 0);
                float p[4];
                #pragma unroll
                for (int r = 0; r < 4; ++r) p[r] = EXP2F(sv[r] * SC2);
                if (st == nt) {
                    #pragma unroll
                    for (int r = 0; r < 4; ++r) p[r] = (lg * 4 + r <= lr) ? p[r] : 0.f;
                }
                uint2v d;
                d[0] = pkbf(p[0], p[1]);
                d[1] = pkbf(p[2], p[3]);
                *reinterpret_cast<uint2v*>(
                    Pb + ((nt * 16 + lr) << 7) + ((st * 32 + lg * 8) ^ rswP)) = d;
            }
        }
        {   // zero tiles read by PV: (st=1,nt=0), (st=3,nt=2)
            uint2v z2; z2[0] = 0; z2[1] = 0;
            *reinterpret_cast<uint2v*>(Pb + (lr << 7) + ((32 + lg * 8) ^ rswP)) = z2;
            *reinterpret_cast<uint2v*>(Pb + ((32 + lr) << 7) + ((96 + lg * 8) ^ rswP)) = z2;
        }
        asm volatile("" ::: "memory");

        // PV: O^T = [V^T; ones] * P   (rows 8,12 of O^T = column sums l)
        f32x4 o[4] = {zf, zf, zf, zf};
        #pragma unroll
        for (int ks = 0; ks < 2; ++ks) {
            int vr = min(cb + lr, 127);
            bf16x8 vf = as_bf(*reinterpret_cast<const short8*>(
                sm + SV + (vr << 7) + ((ks * 64 + lg * 16) ^ ((vr & 7) << 4))));
            if (lr == 8 || lr == 12) vf = as_bf(ones8);
            #pragma unroll
            for (int nt = 0; nt < 4; ++nt) {
                if (nt < 2 * ks) continue;
                bf16x8 pf = as_bf(*reinterpret_cast<const short8*>(
                    Pb + ((nt * 16 + lr) << 7) + ((ks * 64 + lg * 16) ^ rswP)));
                o[nt] = __builtin_amdgcn_mfma_f32_16x16x32_bf16(vf, pf, o[nt], 0, 0, 0);
            }
        }
        asm volatile("" ::: "memory");

        // finalize: l from ones-row (lg2:row8, lg3:row12), write attn-out into Q cols
        #pragma unroll
        for (int nt = 0; nt < 4; ++nt) {
            float l   = __shfl_xor(o[nt][0], 32);
            float inv = RCPF(l);
            if (lg < 2) {
                int t_ = nt * 16 + lr;
                uint2v d;
                d[0] = pkbf(o[nt][0] * inv, o[nt][1] * inv);
                d[1] = pkbf(o[nt][2] * inv, o[nt][3] * inv);
                *reinterpret_cast<uint2v*>(
                    sm + SQK + (t_ << 9) + ((cbB + lg * 8) ^ rswQ)) = d;
            }
        }
    }
    __syncthreads();

    // ---------- GEMM2: out = aout[64][128] @ Wo[128][128] + bo, relu ----------
    f32x4 acc2[4][2];
    #pragma unroll
    for (int m = 0; m < 4; ++m)
        #pragma unroll
        for (int i = 0; i < 2; ++i)
            acc2[m][i] = zf;

    #pragma unroll
    for (int ks = 0; ks < 4; ++ks) {
        bf16x8 a2[4];
        #pragma unroll
        for (int m = 0; m < 4; ++m)
            a2[m] = as_bf(*reinterpret_cast<const short8*>(
                sm + SQK + ((m * 16 + lr) << 9) + ((ks * 64 + lg * 16) ^ rswQ)));
        bf16x8 b2[2];
        #pragma unroll
        for (int i = 0; i < 2; ++i)
            b2[i] = as_bf(*reinterpret_cast<const short8*>(
                wo2 + (size_t)ks * 4096 + (size_t)((w + 4 * i) * 16 + lr) * 32 + lg * 8));
        #pragma unroll
        for (int m = 0; m < 4; ++m)
            #pragma unroll
            for (int i = 0; i < 2; ++i)
                acc2[m][i] = __builtin_amdgcn_mfma_f32_16x16x32_bf16(a2[m], b2[i], acc2[m][i], 0, 0, 0);
    }

    float* obase = out + (size_t)(b * 16384 + n) * 128;
    #pragma unroll
    for (int i = 0; i < 2; ++i) {
        int c = (w + 4 * i) * 16 + lr;
        float bias = bo[c];
        #pragma unroll
        for (int m = 0; m < 4; ++m)
            #pragma unroll
            for (int r = 0; r < 4; ++r) {
                int tt = m * 16 + lg * 4 + r;
                obase[(size_t)tt * 32768 + c] = fmaxf(acc2[m][i][r] + bias, 0.f);
            }
    }
}

extern "C" void kernel_launch(void* const* d_in, const int* in_sizes, int n_in,
                              void* d_out, int out_size, void* d_ws, size_t ws_size,
                              hipStream_t stream) {
    const float* X   = (const float*)d_in[0];
    const float* STE = (const float*)d_in[1];
    const float* Wq  = (const float*)d_in[2];
    const float* bq  = (const float*)d_in[3];
    const float* Wk  = (const float*)d_in[4];
    const float* bk  = (const float*)d_in[5];
    const float* Wv  = (const float*)d_in[6];
    const float* bv  = (const float*)d_in[7];
    const float* Wo  = (const float*)d_in[8];
    const float* bo  = (const float*)d_in[9];
    float* out = (float*)d_out;

    unsigned short* wq2 = (unsigned short*)d_ws;      // 384*256 bf16
    unsigned short* wo2 = wq2 + 384 * 256;            // 128*128 bf16

    prep_weights<<<448, 256, 0, stream>>>(Wq, Wk, Wv, Wo, wq2, wo2);
    fused_attn<<<2048, 256, 0, stream>>>(X, STE, bq, bk, bv, bo, wq2, wo2, out);
}